// Round 1
// baseline (159.236 us; speedup 1.0000x reference)
//
#include <hip/hip_runtime.h>
#include <hip/hip_bf16.h>

// MultiScaleSparseSelfAttention, algebraically reduced:
//  - roll acts on (head, flatN) axes; softmax is shift-invariant over keys
//  - sum over dw collapses to P_{h,g} @ Wsum_u, Wsum = sum of v rows at {-4,-2,0,2,4}
//  - dh=+2 and dh=-2 identical (mod 4) -> weight 2
// 25 attentions/head -> 4 attentions/head.

typedef __bf16 bf16x8 __attribute__((ext_vector_type(8)));
typedef float f32x4 __attribute__((ext_vector_type(4)));

#define MFMA16(A,B,C) __builtin_amdgcn_mfma_f32_16x16x32_bf16(A,B,C,0,0,0)

__device__ __forceinline__ bf16x8 ld8(const __bf16* p){ return *reinterpret_cast<const bf16x8*>(p); }

struct ProjArgs { const float* W[6]; const float* Bz[6]; };

// ---------------- projection: Q,K,V bf16 [s][b][h][n][d] ----------------
// grid 768 = 64 rowgroups(64 rows) x 12 colgroups(64 of 768 concat q|k|v cols)
__global__ __launch_bounds__(256) void proj_k(const float* __restrict__ x0,
                                              const float* __restrict__ x1,
                                              ProjArgs args,
                                              __bf16* __restrict__ Qb,
                                              __bf16* __restrict__ Kb,
                                              __bf16* __restrict__ Vb)
{
    int bid = blockIdx.x;
    int cg = bid % 12, rg = bid / 12;
    int tid = threadIdx.x, wv = tid >> 6, l = tid & 63;
    int lr = l & 15, lg = l >> 4;
    int s = rg >> 5;                       // 2048 rows per scale
    const float* xs = s ? x1 : x0;
    int p = cg >> 2;                       // 0=q 1=k 2=v
    const float* Wp = args.W[s*3 + p];
    const float* bp = args.Bz[s*3 + p];
    int rowbase = rg*64 + wv*16;
    int colbase = (cg & 3)*64;

    f32x4 acc[4];
    #pragma unroll
    for (int t=0;t<4;t++) acc[t] = f32x4{0.f,0.f,0.f,0.f};

    int arow = (rowbase + lr) & 2047;      // row within [B*N] for this scale
    #pragma unroll
    for (int kk=0; kk<8; kk++){
        int ci = kk*32 + lg*8;
        const float* ap = xs + (size_t)arow*256 + ci;
        f32x4 a0 = *reinterpret_cast<const f32x4*>(ap);
        f32x4 a1 = *reinterpret_cast<const f32x4*>(ap+4);
        bf16x8 af;
        #pragma unroll
        for (int j=0;j<4;j++){ af[j] = (__bf16)a0[j]; af[4+j] = (__bf16)a1[j]; }
        #pragma unroll
        for (int ct=0; ct<4; ct++){
            int co = colbase + ct*16 + lr;
            const float* wp2 = Wp + (size_t)co*256 + ci;
            f32x4 b0 = *reinterpret_cast<const f32x4*>(wp2);
            f32x4 b1 = *reinterpret_cast<const f32x4*>(wp2+4);
            bf16x8 bfv;
            #pragma unroll
            for (int j=0;j<4;j++){ bfv[j] = (__bf16)b0[j]; bfv[4+j] = (__bf16)b1[j]; }
            acc[ct] = MFMA16(af, bfv, acc[ct]);
        }
    }
    __bf16* dst = (p==0) ? Qb : (p==1) ? Kb : Vb;
    #pragma unroll
    for (int ct=0; ct<4; ct++){
        int co = colbase + ct*16 + lr;
        float bias = bp[co];
        int h = co >> 6, d = co & 63;
        #pragma unroll
        for (int i=0;i<4;i++){
            int gr = rowbase + lg*4 + i;
            int b = (gr >> 10) & 1, n = gr & 1023;
            size_t idx = ((((size_t)s*2 + b)*4 + h)*1024 + n)*64 + d;
            dst[idx] = (__bf16)(acc[ct][i] + bias);
        }
    }
}

// ------------- smoothed V, transposed: WT[s][b][u][d][n] bf16 -------------
// grid 256 = 16 sbu x 16 n-tiles(64)
__global__ __launch_bounds__(256) void smooth_k(const __bf16* __restrict__ Vb,
                                                __bf16* __restrict__ WT)
{
    __shared__ __bf16 Vt[72][66];          // stride 66 -> conflict-free col reads
    int bid = blockIdx.x;
    int sbu = bid >> 4, n0 = (bid & 15)*64;
    int tid = threadIdx.x;
    const __bf16* Vs = Vb + (size_t)sbu*1024*64;
    for (int idx = tid; idx < 576; idx += 256){
        int row = idx >> 3, ch = idx & 7;
        int n = (n0 - 4 + row) & 1023;     // circular
        bf16x8 v = ld8(Vs + (size_t)n*64 + ch*8);
        #pragma unroll
        for (int j=0;j<8;j++) Vt[row][ch*8+j] = v[j];
    }
    __syncthreads();
    int w = tid >> 6, l = tid & 63;
    __bf16* dst = WT + (size_t)sbu*64*1024;
    #pragma unroll
    for (int it=0; it<16; it++){
        int d = it*4 + w;
        float sum = 0.f;
        #pragma unroll
        for (int j=0;j<5;j++) sum += (float)Vt[l + j*2][d];   // n-4..n+4 step 2
        dst[(size_t)d*1024 + n0 + l] = (__bf16)sum;
    }
}

// ---------------- attention: per (s,b,h,dh,64-row q tile) ----------------
// grid 1024 x 256thr (4 waves, 16 q rows each). Writes f32 partials[s*4+dh].
__global__ __launch_bounds__(256) void attn_k(const __bf16* __restrict__ Qb,
                                              const __bf16* __restrict__ Kb,
                                              const __bf16* __restrict__ WT,
                                              float* __restrict__ parts)
{
    int bid = blockIdx.x;
    int qt = bid & 15, dhi = (bid>>4)&3, h = (bid>>6)&3, b = (bid>>8)&1, s = (bid>>9)&1;
    int dhv = (dhi==2) ? -1 : (dhi==3 ? 2 : dhi);   // {0,1,-1,2}
    int g = (h - dhv + 4) & 3;                      // K head
    int u = (h + dhv + 4) & 3;                      // V head
    float wgt = (dhi==3) ? 2.f : 1.f;               // dh=+-2 merged
    int tid = threadIdx.x, wv = tid>>6, l = tid&63, lr = l&15, lg = l>>4;
    int sb = s*2 + b;
    const __bf16* Qw = Qb + (((size_t)sb*4 + h)*1024 + qt*64 + wv*16)*64;
    const __bf16* Kg = Kb + ((size_t)sb*4 + g)*1024*64;
    const __bf16* Wu = WT + ((size_t)sb*4 + u)*64*1024;
    bf16x8 qa0 = ld8(Qw + lr*64 + lg*8);
    bf16x8 qa1 = ld8(Qw + lr*64 + 32 + lg*8);

    __shared__ alignas(16) __bf16 Plds[4][16][40];  // stride 40: pad vs bank conflicts
    __bf16* Pw = &Plds[wv][0][0];

    const f32x4 z = {0.f,0.f,0.f,0.f};
    f32x4 pv[4] = {z,z,z,z};
    float ds[4] = {0.f,0.f,0.f,0.f};
    const float c2 = 0.09016844f;                   // (1/16)*log2(e)

    for (int kt=0; kt<1024; kt+=32){
        const __bf16* k0 = Kg + (size_t)(kt + lr)*64 + lg*8;
        bf16x8 kf00 = ld8(k0),        kf01 = ld8(k0 + 32);
        bf16x8 kf10 = ld8(k0 + 1024), kf11 = ld8(k0 + 1056);  // +16 key rows
        f32x4 s0 = MFMA16(qa0, kf00, z); s0 = MFMA16(qa1, kf01, s0);
        f32x4 s1 = MFMA16(qa0, kf10, z); s1 = MFMA16(qa1, kf11, s1);
        #pragma unroll
        for (int i=0;i<4;i++){
            float e0 = __builtin_amdgcn_exp2f(s0[i]*c2);
            float e1 = __builtin_amdgcn_exp2f(s1[i]*c2);
            ds[i] += e0 + e1;
            Pw[(lg*4+i)*40 + lr]      = (__bf16)e0;   // P[qrow][key]
            Pw[(lg*4+i)*40 + 16 + lr] = (__bf16)e1;
        }
        bf16x8 pa = *reinterpret_cast<const bf16x8*>(Pw + lr*40 + lg*8);
        #pragma unroll
        for (int dt=0; dt<4; dt++){
            bf16x8 wb = ld8(Wu + (size_t)(dt*16 + lr)*1024 + kt + lg*8);
            pv[dt] = MFMA16(pa, wb, pv[dt]);
        }
        __syncthreads();   // keep waves converged for L1 reuse of K/WT
    }
    #pragma unroll
    for (int i=0;i<4;i++){
        #pragma unroll
        for (int m=1;m<16;m<<=1) ds[i] += __shfl_xor(ds[i], m, 64);
    }
    float* pp = parts + (size_t)(s*4 + dhi)*524288;
    #pragma unroll
    for (int i=0;i<4;i++){
        float inv = wgt / ds[i];
        int n = qt*64 + wv*16 + lg*4 + i;
        float* row = pp + ((size_t)b*1024 + n)*256 + h*64;
        #pragma unroll
        for (int dt=0; dt<4; dt++){
            row[dt*16 + lr] = pv[dt][i] * inv;
        }
    }
}

// ---------------- reduce 8 partial slots -> out f32 ----------------
__global__ __launch_bounds__(256) void reduce_k(const f32x4* __restrict__ parts,
                                                f32x4* __restrict__ out)
{
    int idx = blockIdx.x*256 + threadIdx.x;        // 131072 float4
    f32x4 a = parts[idx];
    #pragma unroll
    for (int p=1;p<8;p++) a += parts[(size_t)p*131072 + idx];
    out[idx] = a;
}

extern "C" void kernel_launch(void* const* d_in, const int* in_sizes, int n_in,
                              void* d_out, int out_size, void* d_ws, size_t ws_size,
                              hipStream_t stream)
{
    const float* x0 = (const float*)d_in[0];
    const float* x1 = (const float*)d_in[1];
    ProjArgs pa;
    for (int s=0;s<2;s++) for (int p=0;p<3;p++){
        pa.W[s*3+p]  = (const float*)d_in[2 + s*6 + p*2];
        pa.Bz[s*3+p] = (const float*)d_in[3 + s*6 + p*2];
    }
    char* wsb = (char*)d_ws;
    __bf16* Qb = (__bf16*)(wsb);                 // 2 MB
    __bf16* Kb = (__bf16*)(wsb + (2u<<20));      // 2 MB
    __bf16* Vb = (__bf16*)(wsb + (4u<<20));      // 2 MB
    __bf16* WT = (__bf16*)(wsb + (6u<<20));      // 2 MB
    float*  parts = (float*)(wsb + (8u<<20));    // 16 MB

    proj_k<<<768, 256, 0, stream>>>(x0, x1, pa, Qb, Kb, Vb);
    smooth_k<<<256, 256, 0, stream>>>(Vb, WT);
    attn_k<<<1024, 256, 0, stream>>>(Qb, Kb, WT, parts);
    reduce_k<<<512, 256, 0, stream>>>((const f32x4*)parts, (f32x4*)d_out);
}